// Round 1
// baseline (206.146 us; speedup 1.0000x reference)
//
#include <hip/hip_runtime.h>

// LIF constants (match reference)
constexpr int   SEQ      = 100;
constexpr float DT_TAUI  = 0.1f;   // DT * TAU_MEM_INV
constexpr float V_TH     = 1.0f;

typedef float f32x2 __attribute__((ext_vector_type(2)));

// One thread per 2 neurons. v, I in registers; 100 coalesced 8B stores per
// thread. CHANGE vs prev: stores are NON-TEMPORAL (nt) — output has zero
// reuse, so bypass L2 write-allocate/evict serialization and stream the
// 210 MB to HBM. 1024 blocks -> 16 waves/CU kept for store MLP.
__global__ __launch_bounds__(256) void lif_encode_kernel(
    const float* __restrict__ in, float* __restrict__ out, int n2)
{
    int i = blockIdx.x * blockDim.x + threadIdx.x;
    if (i >= n2) return;

    const f32x2* in2  = reinterpret_cast<const f32x2*>(in);
    f32x2*       out2 = reinterpret_cast<f32x2*>(out) + i;

    f32x2 I = in2[i];
    f32x2 v = {0.f, 0.f};

    for (int t = 0; t < SEQ; ++t) {
        // v' = v + 0.1*(I - v)
        v.x += DT_TAUI * (I.x - v.x);
        v.y += DT_TAUI * (I.y - v.y);
        // z = H(v' - v_th); v'' = v' - z*(v' - v_reset), v_reset = 0
        f32x2 z;
        z.x = (v.x > V_TH) ? 1.f : 0.f;
        z.y = (v.y > V_TH) ? 1.f : 0.f;
        v.x -= z.x * v.x;
        v.y -= z.y * v.y;
        __builtin_nontemporal_store(z, out2);   // global_store_dwordx2 ... nt
        out2 += n2;
    }
}

extern "C" void kernel_launch(void* const* d_in, const int* in_sizes, int n_in,
                              void* d_out, int out_size, void* d_ws, size_t ws_size,
                              hipStream_t stream)
{
    const float* in  = reinterpret_cast<const float*>(d_in[0]);
    float*       out = reinterpret_cast<float*>(d_out);
    int n  = in_sizes[0];      // 64*8192 = 524288
    int n2 = n / 2;            // 262144 threads
    int block = 256;
    int grid  = (n2 + block - 1) / block;   // 1024
    lif_encode_kernel<<<grid, block, 0, stream>>>(in, out, n2);
}